// Round 10
// baseline (138.585 us; speedup 1.0000x reference)
//
#include <hip/hip_runtime.h>

#define NB 32      // batch
#define NC 256     // planes
#define NO 128     // inplanes (output channels)
#define HH 28
#define HW 784     // 28*28
#define OH 56

typedef unsigned short u16;
typedef __attribute__((ext_vector_type(8))) short bf16x8;
typedef __attribute__((ext_vector_type(4))) float f32x4;
typedef __attribute__((ext_vector_type(8))) unsigned short u16x8;

#define MFMA(A,B,C) __builtin_amdgcn_mfma_f32_16x16x32_bf16(A,B,C,0,0,0)

__device__ __forceinline__ u16 f2bf(float f) {
    unsigned u = __float_as_uint(f);
    unsigned r = (u + 0x7fffu + ((u >> 16) & 1u)) >> 16;
    return (u16)r;
}

// ---------------------------------------------------------------------------
// zero-fill (16B granules)
// ---------------------------------------------------------------------------
__global__ void k_zero(uint4* __restrict__ p, int n) {
    int g = blockIdx.x * 256 + threadIdx.x;
    if (g < n) p[g] = make_uint4(0, 0, 0, 0);
}

// ---------------------------------------------------------------------------
// Fused weight packs:
//  blocks [0,288):   wT2[tap][cb][o][ci]  = w2[c][o][2-dy][2-dx]
//  blocks [288,432): wc2T[s][cb][o][ci]   = w1[c][o][tap_s], s->taps {0,2,6,8,1,7,3,5,4}
//  blocks [432,464): wupT[p][kb][o][ki]   = wup[k][o][p]
// ---------------------------------------------------------------------------
__global__ void k_pack_weights(const float* __restrict__ w2, const float* __restrict__ w1,
                               const float* __restrict__ wup,
                               u16* __restrict__ wT2, u16* __restrict__ wc2T,
                               u16* __restrict__ wupT) {
    int blk = blockIdx.x;
    if (blk < 288) {
        int g = blk * 256 + threadIdx.x;          // 9*32*256
        int o = g & 255;
        int cb = (g >> 8) & 31;
        int tap = g >> 13;
        int u = 2 - tap / 3, v = 2 - tap % 3;
        u16x8 out;
#pragma unroll
        for (int ci = 0; ci < 8; ++ci) {
            int c = cb * 8 + ci;
            out[ci] = f2bf(w2[((c * NC + o) * 3 + u) * 3 + v]);
        }
        *(u16x8*)(wT2 + (size_t)g * 8) = out;
    } else if (blk < 432) {
        const int taps[9] = {0, 2, 6, 8, 1, 7, 3, 5, 4};
        int g = (blk - 288) * 256 + threadIdx.x;  // 9*32*128
        int o = g & 127;
        int cb = (g >> 7) & 31;
        int s = g >> 12;
        int tap = taps[s];
        u16x8 out;
#pragma unroll
        for (int ci = 0; ci < 8; ++ci) {
            int c = cb * 8 + ci;
            out[ci] = f2bf(w1[(c * NO + o) * 9 + tap]);
        }
        *(u16x8*)(wc2T + (size_t)g * 8) = out;
    } else {
        int g = (blk - 432) * 256 + threadIdx.x;  // 4*16*128
        int o = g & 127;
        int kb = (g >> 7) & 15;
        int p = g >> 11;
        u16x8 out;
#pragma unroll
        for (int ki = 0; ki < 8; ++ki) {
            int k = kb * 8 + ki;
            out[ki] = f2bf(wup[(k * NO + o) * 4 + p]);
        }
        *(u16x8*)(wupT + (size_t)g * 8) = out;
    }
}

// ---------------------------------------------------------------------------
// Pack x: xT2[b][ry 0..29][cb][cx 0..31][ci], value = x[b][c][ry-1][cx-1]+b1a or 0
// ---------------------------------------------------------------------------
__global__ void k_pack_x(const float* __restrict__ x, const float* __restrict__ pb1a,
                         u16* __restrict__ xT2) {
    int g = blockIdx.x * 256 + threadIdx.x;          // 32*30*32*32 = 983040
    float b1a = pb1a[0];
    int cx = g & 31;
    int cb = (g >> 5) & 31;
    int bry = g >> 10;
    int b = bry / 30;
    int ry = bry - b * 30;
    int y = ry - 1, xx = cx - 1;
    bool valid = (y >= 0 && y < HH && xx >= 0 && xx < HH);
    const float* xb = x + (size_t)b * NC * HW + (valid ? y * 28 + xx : 0);
    u16x8 out;
#pragma unroll
    for (int ci = 0; ci < 8; ++ci) {
        float f = valid ? xb[(cb * 8 + ci) * HW] + b1a : 0.f;
        out[ci] = f2bf(f);
    }
    *(u16x8*)(xT2 + (size_t)g * 8) = out;
}

// ---------------------------------------------------------------------------
// Gather-pack selected channels: xupT[b][qy][kb][cx][ki] = x[b][sel[k]][qy][cx]+b1a
// ---------------------------------------------------------------------------
__global__ void k_pack_xup(const float* __restrict__ x, const int* __restrict__ sel,
                           const float* __restrict__ pb1a, u16* __restrict__ xupT) {
    int g = blockIdx.x * 256 + threadIdx.x;          // 32*28*16*32 = 458752
    float b1a = pb1a[0];
    int cx = g & 31;
    int kb = (g >> 5) & 15;
    int qyb = g >> 9;
    int b = qyb / 28;
    int qy = qyb - b * 28;
    bool valid = cx < 28;
    const int* selb = sel + b * NO;
    const float* xb = x + (size_t)b * NC * HW + qy * 28 + (valid ? cx : 0);
    u16x8 out;
#pragma unroll
    for (int ki = 0; ki < 8; ++ki) {
        int ch = selb[kb * 8 + ki];
        float f = valid ? xb[ch * HW] + b1a : 0.f;
        out[ki] = f2bf(f);
    }
    *(u16x8*)(xupT + (size_t)g * 8) = out;
}

// ---------------------------------------------------------------------------
// K1: per-(b,c) range
// ---------------------------------------------------------------------------
__global__ void k_range(const float* __restrict__ x, float* __restrict__ rng) {
    int bc = blockIdx.x;
    int t = threadIdx.x;
    const float* p = x + (size_t)bc * HW;
    float mx = -1e30f, mn = 1e30f;
    for (int i = t; i < HW; i += 256) {
        float v = p[i];
        mx = fmaxf(mx, v);
        mn = fminf(mn, v);
    }
    __shared__ float smx[256], smn[256];
    smx[t] = mx; smn[t] = mn;
    __syncthreads();
    for (int s = 128; s > 0; s >>= 1) {
        if (t < s) {
            smx[t] = fmaxf(smx[t], smx[t + s]);
            smn[t] = fminf(smn[t], smn[t + s]);
        }
        __syncthreads();
    }
    if (t == 0) rng[bc] = smx[0] - smn[0];
}

// ---------------------------------------------------------------------------
// K2: stable argsort rank; keep top half ascending
// ---------------------------------------------------------------------------
__global__ void k_select(const float* __restrict__ rng, int* __restrict__ sel) {
    int b = blockIdx.x;
    int c = threadIdx.x;
    __shared__ float s[NC];
    s[c] = rng[b * NC + c];
    __syncthreads();
    float v = s[c];
    int rank = 0;
    for (int j = 0; j < NC; ++j) {
        float u = s[j];
        rank += (u < v) || (u == v && j < c);
    }
    if (rank >= NC / 2) sel[b * (NC / 2) + (rank - NC / 2)] = c;
}

// ---------------------------------------------------------------------------
// conv1 via MFMA, phase-pipelined:
//  A resident in LDS per 128-ch half (48KB, restaged once mid-kernel),
//  B streamed through double-buffered LDS (24 phases of (c0:32ch, dy),
//  48KB per buffer). T14 async-split per phase:
//    {issue B(p+1) global loads} -> {compute(p): 12 A-ds + 12 B-ds + 48 MFMA}
//    -> {ds_write B(p+1)} -> barrier.
//  Block: b x rg(7), 512 thr, 8 waves = 2wpi x 4wo, wave = 64px x 64o.
//  LDS total 147456 B -> 1 block/CU.
// ---------------------------------------------------------------------------
__global__ __launch_bounds__(512, 2) void k_conv1_mfma(
    const u16* __restrict__ xT2, const u16* __restrict__ wT2,
    const float* __restrict__ pb1b, const float* __restrict__ pb2a,
    u16* __restrict__ r1T)
{
    __shared__ uint4 sA[3072];        // 48KB: [row6][cb16][cx32][ci8]
    __shared__ uint4 sB[2][3072];     // 2x48KB: [dx3][cb4][o256][ci8]

    int tid = threadIdx.x;
    int wave = tid >> 6, lane = tid & 63;
    int wpi = wave >> 2;              // 0..1
    int wo = wave & 3;                // 0..3
    int l15 = lane & 15, lg = lane >> 4;

    int b = blockIdx.x / 7;
    int rg = blockIdx.x - b * 7;
    int y0 = rg * 4;

    float b1b = pb1b[0], b2a = pb2a[0];

    const uint4* gx = (const uint4*)xT2;
    const uint4* gw = (const uint4*)wT2;

    // prologue: stage A(half 0) + B(phase 0: c0=0, dy=0)
    uint4 ra[6], rb[6];
#pragma unroll
    for (int i = 0; i < 6; ++i)
        ra[i] = gx[(b * 30 + y0 + i) * 1024 + tid];
#pragma unroll
    for (int i = 0; i < 6; ++i) {
        int u4 = i * 512 + tid;
        int dx = u4 >> 10, wit = u4 & 1023;
        rb[i] = gw[dx * 8192 + wit];
    }
#pragma unroll
    for (int i = 0; i < 6; ++i) sA[i * 512 + tid] = ra[i];
#pragma unroll
    for (int i = 0; i < 6; ++i) sB[0][i * 512 + tid] = rb[i];
    __syncthreads();

    f32x4 acc[4][4] = {};             // [pt = m*2+hx][ot]
    const u16* sAu = (const u16*)sA;

    for (int p = 0; p < 24; ++p) {
        int pm = p - (p / 12) * 12;
        int c0 = (p / 12) * 128 + (pm / 3) * 32;
        int dy = pm - (pm / 3) * 3;
        int np = p + 1;
        bool haveNext = (np < 24);
        bool atrans = (np == 12);

        // issue next-phase B loads (and A-half-1 loads at the transition)
        if (haveNext) {
            int npm = np - (np / 12) * 12;
            int nc0 = (np / 12) * 128 + (npm / 3) * 32;
            int ndy = npm - (npm / 3) * 3;
#pragma unroll
            for (int i = 0; i < 6; ++i) {
                int u4 = i * 512 + tid;
                int dx = u4 >> 10, wit = u4 & 1023;
                rb[i] = gw[(ndy * 3 + dx) * 8192 + (nc0 >> 3) * 256 + wit];
            }
        }
        if (atrans) {
#pragma unroll
            for (int i = 0; i < 6; ++i)
                ra[i] = gx[(b * 30 + y0 + i) * 1024 + 512 + tid];
        }

        // compute(p) from sA + sB[p&1]
        {
            const u16* sBu = (const u16*)sB[p & 1];
            int cbl = (c0 & 127) >> 3;          // 0,4,8,12
#pragma unroll
            for (int dx = 0; dx < 3; ++dx) {
                bf16x8 ww[4], aa[2][2];
#pragma unroll
                for (int ot = 0; ot < 4; ++ot)
                    ww[ot] = *(const bf16x8*)(sBu + dx * 8192 + lg * 2048 +
                                              (wo * 64 + ot * 16 + l15) * 8);
#pragma unroll
                for (int m = 0; m < 2; ++m)
#pragma unroll
                    for (int hx = 0; hx < 2; ++hx)
                        aa[m][hx] = *(const bf16x8*)(sAu +
                            (2 * wpi + m + dy) * 4096 + (cbl + lg) * 256 +
                            (hx * 16 + l15 + dx) * 8);
#pragma unroll
                for (int m = 0; m < 2; ++m)
#pragma unroll
                    for (int hx = 0; hx < 2; ++hx)
#pragma unroll
                        for (int ot = 0; ot < 4; ++ot)
                            acc[m * 2 + hx][ot] =
                                MFMA(aa[m][hx], ww[ot], acc[m * 2 + hx][ot]);
            }
        }

        // write staged B for next phase, then phase barrier
        if (haveNext) {
#pragma unroll
            for (int i = 0; i < 6; ++i) sB[np & 1][i * 512 + tid] = rb[i];
        }
        __syncthreads();
        if (atrans) {
#pragma unroll
            for (int i = 0; i < 6; ++i) sA[i * 512 + tid] = ra[i];
            __syncthreads();
        }
    }

    // epilogue: relu(acc+b1b)+b2a -> r1T[b][y+1][o/8][x+1][o%8]
#pragma unroll
    for (int m = 0; m < 2; ++m)
#pragma unroll
        for (int hx = 0; hx < 2; ++hx) {
            int y = y0 + 2 * wpi + m;
            int x0 = hx * 16 + lg * 4;
            if (x0 >= 28) continue;
#pragma unroll
            for (int ot = 0; ot < 4; ++ot) {
                int o = wo * 64 + ot * 16 + l15;
                size_t base = ((((size_t)b * 30 + y + 1) * 32 + (o >> 3)) * 32 + (x0 + 1)) * 8 + (o & 7);
#pragma unroll
                for (int r = 0; r < 4; ++r) {
                    float f = fmaxf(acc[m * 2 + hx][ot][r] + b1b, 0.f) + b2a;
                    r1T[base + (size_t)r * 8] = f2bf(f);
                }
            }
        }
}

// ---------------------------------------------------------------------------
// conv2 + upsample via MFMA (unchanged control this round).
// ---------------------------------------------------------------------------
__global__ __launch_bounds__(512, 2) void k_conv2_mfma(
    const u16* __restrict__ r1T, const u16* __restrict__ xupT,
    const u16* __restrict__ wc2T, const u16* __restrict__ wupT,
    const float* __restrict__ pscale, const float* __restrict__ pb2b,
    float* __restrict__ out)
{
    int tid = threadIdx.x;
    int wave = tid >> 6, lane = tid & 63;
    int wpi = wave >> 2;
    int wo = wave & 3;
    int l15 = lane & 15, lg = lane >> 4;

    int b = blockIdx.x / 7;
    int rg = blockIdx.x - b * 7;
    int y0 = rg * 4;

    float scale = pscale[0], b2b = pb2b[0];

    f32x4 acc[4][4][2] = {};   // [parity][pixel-tile][o-tile]

    const char* rp = (const char*)r1T;
    const char* wp = (const char*)wc2T;

    int aBase[4];
#pragma unroll
    for (int pt = 0; pt < 4; ++pt) {
        int qy = y0 + 2 * wpi + (pt >> 1);
        int qt = pt & 1;
        aBase[pt] = (((b * 30 + qy + 1) * 32 + lg) * 32 + (qt * 16 + l15 + 1)) * 16;
    }
    int bBase = (lg * 128 + wo * 32 + l15) * 16;

    for (int c0 = 0; c0 < 256; c0 += 32) {
        bf16x8 w[9][2];
#pragma unroll
        for (int s = 0; s < 9; ++s)
#pragma unroll
            for (int ot = 0; ot < 2; ++ot)
                w[s][ot] = *(const bf16x8*)(wp + (bBase + s * 65536 + c0 * 256 + ot * 256));
#pragma unroll
        for (int pt = 0; pt < 4; ++pt) {
            const char* ap = rp + (aBase[pt] + c0 * 64);
            bf16x8 aD = *(const bf16x8*)(ap);
            bf16x8 aC = *(const bf16x8*)(ap - 16);
            bf16x8 aB = *(const bf16x8*)(ap - 16384);
            bf16x8 aA = *(const bf16x8*)(ap - 16400);
#pragma unroll
            for (int ot = 0; ot < 2; ++ot) {
                acc[0][pt][ot] = MFMA(aD, w[0][ot], acc[0][pt][ot]);
                acc[0][pt][ot] = MFMA(aC, w[1][ot], acc[0][pt][ot]);
                acc[0][pt][ot] = MFMA(aB, w[2][ot], acc[0][pt][ot]);
                acc[0][pt][ot] = MFMA(aA, w[3][ot], acc[0][pt][ot]);
                acc[1][pt][ot] = MFMA(aD, w[4][ot], acc[1][pt][ot]);
                acc[1][pt][ot] = MFMA(aB, w[5][ot], acc[1][pt][ot]);
                acc[2][pt][ot] = MFMA(aD, w[6][ot], acc[2][pt][ot]);
                acc[2][pt][ot] = MFMA(aC, w[7][ot], acc[2][pt][ot]);
                acc[3][pt][ot] = MFMA(aD, w[8][ot], acc[3][pt][ot]);
            }
        }
    }

    // mid-transform: pad-zero / scale+b2b (before upsample accumulation)
#pragma unroll
    for (int pt = 0; pt < 4; ++pt) {
        int qy = y0 + 2 * wpi + (pt >> 1);
        int qt = pt & 1;
        int qx0 = qt * 16 + lg * 4;
        bool zr = (qy == 0);
#pragma unroll
        for (int ot = 0; ot < 2; ++ot)
#pragma unroll
            for (int r = 0; r < 4; ++r) {
                bool zc = (qx0 + r == 0);
                float a0 = acc[0][pt][ot][r], a1 = acc[1][pt][ot][r];
                float a2 = acc[2][pt][ot][r], a3 = acc[3][pt][ot][r];
                acc[0][pt][ot][r] = (zr || zc) ? 0.f : fmaf(a0, scale, b2b);
                acc[1][pt][ot][r] = zr ? 0.f : fmaf(a1, scale, b2b);
                acc[2][pt][ot][r] = zc ? 0.f : fmaf(a2, scale, b2b);
                acc[3][pt][ot][r] = fmaf(a3, scale, b2b);
            }
    }

    // upsample accumulation
    const char* up = (const char*)xupT;
    const char* wu = (const char*)wupT;
    int uBaseA[4];
#pragma unroll
    for (int pt = 0; pt < 4; ++pt) {
        int qy = y0 + 2 * wpi + (pt >> 1);
        int qt = pt & 1;
        uBaseA[pt] = (((b * 28 + qy) * 16 + lg) * 32 + (qt * 16 + l15)) * 16;
    }
    for (int k0 = 0; k0 < 128; k0 += 32) {
        bf16x8 wb[4][2];
#pragma unroll
        for (int p = 0; p < 4; ++p)
#pragma unroll
            for (int ot = 0; ot < 2; ++ot)
                wb[p][ot] = *(const bf16x8*)(wu + (bBase + p * 32768 + k0 * 256 + ot * 256));
#pragma unroll
        for (int pt = 0; pt < 4; ++pt) {
            bf16x8 aU = *(const bf16x8*)(up + (uBaseA[pt] + k0 * 64));
#pragma unroll
            for (int p = 0; p < 4; ++p)
#pragma unroll
                for (int ot = 0; ot < 2; ++ot)
                    acc[p][pt][ot] = MFMA(aU, wb[p][ot], acc[p][pt][ot]);
        }
    }

    // relu + store
#pragma unroll
    for (int pt = 0; pt < 4; ++pt) {
        int qy = y0 + 2 * wpi + (pt >> 1);
        int qt = pt & 1;
        int qx0 = qt * 16 + lg * 4;
        if (qx0 >= 28) continue;
#pragma unroll
        for (int ot = 0; ot < 2; ++ot) {
            int o = wo * 32 + ot * 16 + l15;
            size_t base = ((size_t)(b * NO + o) * OH + 2 * qy) * OH + 2 * qx0;
#pragma unroll
            for (int r = 0; r < 4; ++r) {
                float2 v0 = { fmaxf(acc[0][pt][ot][r], 0.f), fmaxf(acc[1][pt][ot][r], 0.f) };
                float2 v1 = { fmaxf(acc[2][pt][ot][r], 0.f), fmaxf(acc[3][pt][ot][r], 0.f) };
                *reinterpret_cast<float2*>(&out[base + 2 * r]) = v0;
                *reinterpret_cast<float2*>(&out[base + OH + 2 * r]) = v1;
            }
        }
    }
}

// ---------------------------------------------------------------------------
extern "C" void kernel_launch(void* const* d_in, const int* in_sizes, int n_in,
                              void* d_out, int out_size, void* d_ws, size_t ws_size,
                              hipStream_t stream)
{
    const float* x     = (const float*)d_in[0];
    const float* w2    = (const float*)d_in[1];
    const float* w1    = (const float*)d_in[2];
    const float* wup   = (const float*)d_in[3];
    const float* b1a   = (const float*)d_in[4];
    const float* b1b   = (const float*)d_in[5];
    const float* b2a   = (const float*)d_in[6];
    const float* b2b   = (const float*)d_in[7];
    const float* scale = (const float*)d_in[8];

    char* ws = (char*)d_ws;
    u16* xT2   = (u16*)(ws);                 // 15,728,640 B
    u16* r1T   = (u16*)(ws + 15728640);      // 15,728,640 B
    u16* xupT  = (u16*)(ws + 31457280);      //  7,340,032 B
    u16* wT2   = (u16*)(ws + 38797312);      //  1,179,648 B
    u16* wc2T  = (u16*)(ws + 39976960);      //    589,824 B
    u16* wupT  = (u16*)(ws + 40566784);      //    131,072 B
    float* rng = (float*)(ws + 40697856);    //     32,768 B
    int* sel   = (int*)(ws + 40730624);      //     16,384 B
    float* out = (float*)d_out;

    hipLaunchKernelGGL(k_pack_weights, dim3(464), dim3(256), 0, stream,
                       w2, w1, wup, wT2, wc2T, wupT);
    hipLaunchKernelGGL(k_pack_x,   dim3(3840), dim3(256), 0, stream, x, b1a, xT2);
    hipLaunchKernelGGL(k_range,    dim3(NB * NC), dim3(256), 0, stream, x, rng);
    hipLaunchKernelGGL(k_select,   dim3(NB),   dim3(NC), 0, stream, rng, sel);
    hipLaunchKernelGGL(k_zero,     dim3(3840), dim3(256), 0, stream, (uint4*)r1T, 983040);
    hipLaunchKernelGGL(k_conv1_mfma, dim3(224), dim3(512), 0, stream,
                       xT2, wT2, b1b, b2a, r1T);
    hipLaunchKernelGGL(k_pack_xup, dim3(1792), dim3(256), 0, stream, x, sel, b1a, xupT);
    hipLaunchKernelGGL(k_conv2_mfma, dim3(NB * 7), dim3(512), 0, stream,
                       r1T, xupT, wc2T, wupT, scale, b2b, out);
}

// Round 11
// 126.214 us; speedup vs baseline: 1.0980x; 1.0980x over previous
//
#include <hip/hip_runtime.h>

#define NB 32      // batch
#define NC 256     // planes
#define NO 128     // inplanes (output channels)
#define HH 28
#define HW 784     // 28*28
#define OH 56

typedef unsigned short u16;
typedef __attribute__((ext_vector_type(8))) short bf16x8;
typedef __attribute__((ext_vector_type(4))) float f32x4;
typedef __attribute__((ext_vector_type(8))) unsigned short u16x8;

#define MFMA(A,B,C) __builtin_amdgcn_mfma_f32_16x16x32_bf16(A,B,C,0,0,0)

__device__ __forceinline__ u16 f2bf(float f) {
    unsigned u = __float_as_uint(f);
    unsigned r = (u + 0x7fffu + ((u >> 16) & 1u)) >> 16;
    return (u16)r;
}

// ---------------------------------------------------------------------------
// zero-fill (16B granules)
// ---------------------------------------------------------------------------
__global__ void k_zero(uint4* __restrict__ p, int n) {
    int g = blockIdx.x * 256 + threadIdx.x;
    if (g < n) p[g] = make_uint4(0, 0, 0, 0);
}

// ---------------------------------------------------------------------------
// Fused weight packs:
//  blocks [0,288):   wT2[tap][cb][o][ci]  = w2[c][o][2-dy][2-dx]
//  blocks [288,432): wc2T[s][cb][o][ci]   = w1[c][o][tap_s], s->taps {0,2,6,8,1,7,3,5,4}
//  blocks [432,464): wupT[p][kb][o][ki]   = wup[k][o][p]
// ---------------------------------------------------------------------------
__global__ void k_pack_weights(const float* __restrict__ w2, const float* __restrict__ w1,
                               const float* __restrict__ wup,
                               u16* __restrict__ wT2, u16* __restrict__ wc2T,
                               u16* __restrict__ wupT) {
    int blk = blockIdx.x;
    if (blk < 288) {
        int g = blk * 256 + threadIdx.x;          // 9*32*256
        int o = g & 255;
        int cb = (g >> 8) & 31;
        int tap = g >> 13;
        int u = 2 - tap / 3, v = 2 - tap % 3;
        u16x8 out;
#pragma unroll
        for (int ci = 0; ci < 8; ++ci) {
            int c = cb * 8 + ci;
            out[ci] = f2bf(w2[((c * NC + o) * 3 + u) * 3 + v]);
        }
        *(u16x8*)(wT2 + (size_t)g * 8) = out;
    } else if (blk < 432) {
        const int taps[9] = {0, 2, 6, 8, 1, 7, 3, 5, 4};
        int g = (blk - 288) * 256 + threadIdx.x;  // 9*32*128
        int o = g & 127;
        int cb = (g >> 7) & 31;
        int s = g >> 12;
        int tap = taps[s];
        u16x8 out;
#pragma unroll
        for (int ci = 0; ci < 8; ++ci) {
            int c = cb * 8 + ci;
            out[ci] = f2bf(w1[(c * NO + o) * 9 + tap]);
        }
        *(u16x8*)(wc2T + (size_t)g * 8) = out;
    } else {
        int g = (blk - 432) * 256 + threadIdx.x;  // 4*16*128
        int o = g & 127;
        int kb = (g >> 7) & 15;
        int p = g >> 11;
        u16x8 out;
#pragma unroll
        for (int ki = 0; ki < 8; ++ki) {
            int k = kb * 8 + ki;
            out[ki] = f2bf(wup[(k * NO + o) * 4 + p]);
        }
        *(u16x8*)(wupT + (size_t)g * 8) = out;
    }
}

// ---------------------------------------------------------------------------
// Pack x: xT2[b][ry 0..29][cb][cx 0..31][ci], value = x[b][c][ry-1][cx-1]+b1a or 0
// ---------------------------------------------------------------------------
__global__ void k_pack_x(const float* __restrict__ x, const float* __restrict__ pb1a,
                         u16* __restrict__ xT2) {
    int g = blockIdx.x * 256 + threadIdx.x;          // 32*30*32*32 = 983040
    float b1a = pb1a[0];
    int cx = g & 31;
    int cb = (g >> 5) & 31;
    int bry = g >> 10;
    int b = bry / 30;
    int ry = bry - b * 30;
    int y = ry - 1, xx = cx - 1;
    bool valid = (y >= 0 && y < HH && xx >= 0 && xx < HH);
    const float* xb = x + (size_t)b * NC * HW + (valid ? y * 28 + xx : 0);
    u16x8 out;
#pragma unroll
    for (int ci = 0; ci < 8; ++ci) {
        float f = valid ? xb[(cb * 8 + ci) * HW] + b1a : 0.f;
        out[ci] = f2bf(f);
    }
    *(u16x8*)(xT2 + (size_t)g * 8) = out;
}

// ---------------------------------------------------------------------------
// Gather-pack selected channels: xupT[b][qy][kb][cx][ki] = x[b][sel[k]][qy][cx]+b1a
// ---------------------------------------------------------------------------
__global__ void k_pack_xup(const float* __restrict__ x, const int* __restrict__ sel,
                           const float* __restrict__ pb1a, u16* __restrict__ xupT) {
    int g = blockIdx.x * 256 + threadIdx.x;          // 32*28*16*32 = 458752
    float b1a = pb1a[0];
    int cx = g & 31;
    int kb = (g >> 5) & 15;
    int qyb = g >> 9;
    int b = qyb / 28;
    int qy = qyb - b * 28;
    bool valid = cx < 28;
    const int* selb = sel + b * NO;
    const float* xb = x + (size_t)b * NC * HW + qy * 28 + (valid ? cx : 0);
    u16x8 out;
#pragma unroll
    for (int ki = 0; ki < 8; ++ki) {
        int ch = selb[kb * 8 + ki];
        float f = valid ? xb[ch * HW] + b1a : 0.f;
        out[ki] = f2bf(f);
    }
    *(u16x8*)(xupT + (size_t)g * 8) = out;
}

// ---------------------------------------------------------------------------
// K1: per-(b,c) range
// ---------------------------------------------------------------------------
__global__ void k_range(const float* __restrict__ x, float* __restrict__ rng) {
    int bc = blockIdx.x;
    int t = threadIdx.x;
    const float* p = x + (size_t)bc * HW;
    float mx = -1e30f, mn = 1e30f;
    for (int i = t; i < HW; i += 256) {
        float v = p[i];
        mx = fmaxf(mx, v);
        mn = fminf(mn, v);
    }
    __shared__ float smx[256], smn[256];
    smx[t] = mx; smn[t] = mn;
    __syncthreads();
    for (int s = 128; s > 0; s >>= 1) {
        if (t < s) {
            smx[t] = fmaxf(smx[t], smx[t + s]);
            smn[t] = fminf(smn[t], smn[t + s]);
        }
        __syncthreads();
    }
    if (t == 0) rng[bc] = smx[0] - smn[0];
}

// ---------------------------------------------------------------------------
// K2: stable argsort rank; keep top half ascending
// ---------------------------------------------------------------------------
__global__ void k_select(const float* __restrict__ rng, int* __restrict__ sel) {
    int b = blockIdx.x;
    int c = threadIdx.x;
    __shared__ float s[NC];
    s[c] = rng[b * NC + c];
    __syncthreads();
    float v = s[c];
    int rank = 0;
    for (int j = 0; j < NC; ++j) {
        float u = s[j];
        rank += (u < v) || (u == v && j < c);
    }
    if (rank >= NC / 2) sel[b * (NC / 2) + (rank - NC / 2)] = c;
}

// ---------------------------------------------------------------------------
// conv1 via MFMA, A-slab in LDS (r8 structure, best measured: 45.6 us).
// Block: batch b, 4 output rows, 32 cx, ALL 256 o. Grid 224. LDS 96KB.
// 8 waves = 2(wpi) x 4(wo); wave = 4pt x 4ot, acc 64 VGPR.
// ---------------------------------------------------------------------------
__global__ __launch_bounds__(512, 2) void k_conv1_mfma(
    const u16* __restrict__ xT2, const u16* __restrict__ wT2,
    const float* __restrict__ pb1b, const float* __restrict__ pb2a,
    u16* __restrict__ r1T)
{
    __shared__ u16 sA[6 * 32 * 32 * 8];   // 98304 B
    int tid = threadIdx.x;
    int wave = tid >> 6, lane = tid & 63;
    int wpi = wave >> 2;              // 0..1: rows {2wpi, 2wpi+1}
    int wo = wave & 3;                // 0..3: o-group of 64
    int l15 = lane & 15, lg = lane >> 4;

    int b = blockIdx.x / 7;
    int rg = blockIdx.x - b * 7;
    int y0 = rg * 4;

    float b1b = pb1b[0], b2a = pb2a[0];

    // stage whole A-slab: rows y0..y0+5, all cb/cx/ci -> 6144 uint4 slots
    {
        const uint4* src = (const uint4*)(xT2 + (size_t)(b * 30 + y0) * 8192);
        uint4* dst = (uint4*)sA;
#pragma unroll
        for (int i = 0; i < 12; ++i)
            dst[tid + i * 512] = src[tid + i * 512];
    }
    __syncthreads();

    int bOff[4];
#pragma unroll
    for (int ot = 0; ot < 4; ++ot)
        bOff[ot] = (lg * 256 + (wo * 64 + ot * 16 + l15)) * 16;

    f32x4 acc[4][4] = {};   // [pt = m*2+h][ot]
    const char* wq = (const char*)wT2;
    const char* ap0 = (const char*)sA;

    for (int c0 = 0; c0 < 256; c0 += 32) {
        int cbByte = c0 * 64;             // (c0/8)*512
#pragma unroll
        for (int dy = 0; dy < 3; ++dy) {
#pragma unroll
            for (int dx = 0; dx < 3; ++dx) {
                int tap = dy * 3 + dx;
                bf16x8 w[4];
#pragma unroll
                for (int ot = 0; ot < 4; ++ot)
                    w[ot] = *(const bf16x8*)(wq + (bOff[ot] + tap * 131072 + c0 * 512));
                bf16x8 a[2][2];
#pragma unroll
                for (int m = 0; m < 2; ++m)
#pragma unroll
                    for (int h = 0; h < 2; ++h)
                        a[m][h] = *(const bf16x8*)(ap0 +
                            (2 * wpi + m + dy) * 16384 + cbByte + lg * 512 +
                            (h * 16 + l15 + dx) * 16);
#pragma unroll
                for (int m = 0; m < 2; ++m)
#pragma unroll
                    for (int h = 0; h < 2; ++h)
#pragma unroll
                        for (int ot = 0; ot < 4; ++ot)
                            acc[m * 2 + h][ot] = MFMA(a[m][h], w[ot], acc[m * 2 + h][ot]);
            }
        }
    }

    // epilogue: relu(acc+b1b)+b2a -> r1T[b][y+1][o/8][x+1][o%8]
#pragma unroll
    for (int m = 0; m < 2; ++m)
#pragma unroll
        for (int h = 0; h < 2; ++h) {
            int y = y0 + 2 * wpi + m;
            int x0 = h * 16 + lg * 4;
            if (x0 >= 28) continue;
#pragma unroll
            for (int ot = 0; ot < 4; ++ot) {
                int o = wo * 64 + ot * 16 + l15;
                size_t base = ((((size_t)b * 30 + y + 1) * 32 + (o >> 3)) * 32 + (x0 + 1)) * 8 + (o & 7);
#pragma unroll
                for (int r = 0; r < 4; ++r) {
                    float f = fmaxf(acc[m * 2 + h][ot][r] + b1b, 0.f) + b2a;
                    r1T[base + (size_t)r * 8] = f2bf(f);
                }
            }
        }
}

// ---------------------------------------------------------------------------
// conv2 + upsample via MFMA, A-slab (r1T rows y0..y0+4) staged in LDS (80KB).
// Same r8-style single stage + barrier; B (wc2T/wupT) and xupT stay global.
// ---------------------------------------------------------------------------
__global__ __launch_bounds__(512, 2) void k_conv2_mfma(
    const u16* __restrict__ r1T, const u16* __restrict__ xupT,
    const u16* __restrict__ wc2T, const u16* __restrict__ wupT,
    const float* __restrict__ pscale, const float* __restrict__ pb2b,
    float* __restrict__ out)
{
    __shared__ uint4 sA2[5120];       // 81920 B: padded rows y0..y0+4
    int tid = threadIdx.x;
    int wave = tid >> 6, lane = tid & 63;
    int wpi = wave >> 2;
    int wo = wave & 3;
    int l15 = lane & 15, lg = lane >> 4;

    int b = blockIdx.x / 7;
    int rg = blockIdx.x - b * 7;
    int y0 = rg * 4;

    float scale = pscale[0], b2b = pb2b[0];

    // stage 5-row r1T slab (contiguous 80KB)
    {
        const uint4* src = (const uint4*)(r1T + (size_t)(b * 30 + y0) * 8192);
#pragma unroll
        for (int i = 0; i < 10; ++i)
            sA2[tid + i * 512] = src[tid + i * 512];
    }
    __syncthreads();

    f32x4 acc[4][4][2] = {};   // [parity][pixel-tile][o-tile]

    const char* sp = (const char*)sA2;
    const char* wp = (const char*)wc2T;

    int aBase[4];
#pragma unroll
    for (int pt = 0; pt < 4; ++pt) {
        int rel = 2 * wpi + (pt >> 1) + 1;    // (qy+1) - y0
        int qt = pt & 1;
        aBase[pt] = ((rel * 32 + lg) * 32 + (qt * 16 + l15 + 1)) * 16;
    }
    int bBase = (lg * 128 + wo * 32 + l15) * 16;

    for (int c0 = 0; c0 < 256; c0 += 32) {
        bf16x8 w[9][2];
#pragma unroll
        for (int s = 0; s < 9; ++s)
#pragma unroll
            for (int ot = 0; ot < 2; ++ot)
                w[s][ot] = *(const bf16x8*)(wp + (bBase + s * 65536 + c0 * 256 + ot * 256));
#pragma unroll
        for (int pt = 0; pt < 4; ++pt) {
            const char* ap = sp + (aBase[pt] + c0 * 64);
            bf16x8 aD = *(const bf16x8*)(ap);
            bf16x8 aC = *(const bf16x8*)(ap - 16);
            bf16x8 aB = *(const bf16x8*)(ap - 16384);
            bf16x8 aA = *(const bf16x8*)(ap - 16400);
#pragma unroll
            for (int ot = 0; ot < 2; ++ot) {
                acc[0][pt][ot] = MFMA(aD, w[0][ot], acc[0][pt][ot]);
                acc[0][pt][ot] = MFMA(aC, w[1][ot], acc[0][pt][ot]);
                acc[0][pt][ot] = MFMA(aB, w[2][ot], acc[0][pt][ot]);
                acc[0][pt][ot] = MFMA(aA, w[3][ot], acc[0][pt][ot]);
                acc[1][pt][ot] = MFMA(aD, w[4][ot], acc[1][pt][ot]);
                acc[1][pt][ot] = MFMA(aB, w[5][ot], acc[1][pt][ot]);
                acc[2][pt][ot] = MFMA(aD, w[6][ot], acc[2][pt][ot]);
                acc[2][pt][ot] = MFMA(aC, w[7][ot], acc[2][pt][ot]);
                acc[3][pt][ot] = MFMA(aD, w[8][ot], acc[3][pt][ot]);
            }
        }
    }

    // mid-transform: pad-zero / scale+b2b (before upsample accumulation)
#pragma unroll
    for (int pt = 0; pt < 4; ++pt) {
        int qy = y0 + 2 * wpi + (pt >> 1);
        int qt = pt & 1;
        int qx0 = qt * 16 + lg * 4;
        bool zr = (qy == 0);
#pragma unroll
        for (int ot = 0; ot < 2; ++ot)
#pragma unroll
            for (int r = 0; r < 4; ++r) {
                bool zc = (qx0 + r == 0);
                float a0 = acc[0][pt][ot][r], a1 = acc[1][pt][ot][r];
                float a2 = acc[2][pt][ot][r], a3 = acc[3][pt][ot][r];
                acc[0][pt][ot][r] = (zr || zc) ? 0.f : fmaf(a0, scale, b2b);
                acc[1][pt][ot][r] = zr ? 0.f : fmaf(a1, scale, b2b);
                acc[2][pt][ot][r] = zc ? 0.f : fmaf(a2, scale, b2b);
                acc[3][pt][ot][r] = fmaf(a3, scale, b2b);
            }
    }

    // upsample accumulation (xupT/wupT from global; L2-resident)
    const char* up = (const char*)xupT;
    const char* wu = (const char*)wupT;
    int uBaseA[4];
#pragma unroll
    for (int pt = 0; pt < 4; ++pt) {
        int qy = y0 + 2 * wpi + (pt >> 1);
        int qt = pt & 1;
        uBaseA[pt] = (((b * 28 + qy) * 16 + lg) * 32 + (qt * 16 + l15)) * 16;
    }
    for (int k0 = 0; k0 < 128; k0 += 32) {
        bf16x8 wb[4][2];
#pragma unroll
        for (int p = 0; p < 4; ++p)
#pragma unroll
            for (int ot = 0; ot < 2; ++ot)
                wb[p][ot] = *(const bf16x8*)(wu + (bBase + p * 32768 + k0 * 256 + ot * 256));
#pragma unroll
        for (int pt = 0; pt < 4; ++pt) {
            bf16x8 aU = *(const bf16x8*)(up + (uBaseA[pt] + k0 * 64));
#pragma unroll
            for (int p = 0; p < 4; ++p)
#pragma unroll
                for (int ot = 0; ot < 2; ++ot)
                    acc[p][pt][ot] = MFMA(aU, wb[p][ot], acc[p][pt][ot]);
        }
    }

    // relu + store
#pragma unroll
    for (int pt = 0; pt < 4; ++pt) {
        int qy = y0 + 2 * wpi + (pt >> 1);
        int qt = pt & 1;
        int qx0 = qt * 16 + lg * 4;
        if (qx0 >= 28) continue;
#pragma unroll
        for (int ot = 0; ot < 2; ++ot) {
            int o = wo * 32 + ot * 16 + l15;
            size_t base = ((size_t)(b * NO + o) * OH + 2 * qy) * OH + 2 * qx0;
#pragma unroll
            for (int r = 0; r < 4; ++r) {
                float2 v0 = { fmaxf(acc[0][pt][ot][r], 0.f), fmaxf(acc[1][pt][ot][r], 0.f) };
                float2 v1 = { fmaxf(acc[2][pt][ot][r], 0.f), fmaxf(acc[3][pt][ot][r], 0.f) };
                *reinterpret_cast<float2*>(&out[base + 2 * r]) = v0;
                *reinterpret_cast<float2*>(&out[base + OH + 2 * r]) = v1;
            }
        }
    }
}

// ---------------------------------------------------------------------------
extern "C" void kernel_launch(void* const* d_in, const int* in_sizes, int n_in,
                              void* d_out, int out_size, void* d_ws, size_t ws_size,
                              hipStream_t stream)
{
    const float* x     = (const float*)d_in[0];
    const float* w2    = (const float*)d_in[1];
    const float* w1    = (const float*)d_in[2];
    const float* wup   = (const float*)d_in[3];
    const float* b1a   = (const float*)d_in[4];
    const float* b1b   = (const float*)d_in[5];
    const float* b2a   = (const float*)d_in[6];
    const float* b2b   = (const float*)d_in[7];
    const float* scale = (const float*)d_in[8];

    char* ws = (char*)d_ws;
    u16* xT2   = (u16*)(ws);                 // 15,728,640 B
    u16* r1T   = (u16*)(ws + 15728640);      // 15,728,640 B
    u16* xupT  = (u16*)(ws + 31457280);      //  7,340,032 B
    u16* wT2   = (u16*)(ws + 38797312);      //  1,179,648 B
    u16* wc2T  = (u16*)(ws + 39976960);      //    589,824 B
    u16* wupT  = (u16*)(ws + 40566784);      //    131,072 B
    float* rng = (float*)(ws + 40697856);    //     32,768 B
    int* sel   = (int*)(ws + 40730624);      //     16,384 B
    float* out = (float*)d_out;

    hipLaunchKernelGGL(k_pack_weights, dim3(464), dim3(256), 0, stream,
                       w2, w1, wup, wT2, wc2T, wupT);
    hipLaunchKernelGGL(k_pack_x,   dim3(3840), dim3(256), 0, stream, x, b1a, xT2);
    hipLaunchKernelGGL(k_range,    dim3(NB * NC), dim3(256), 0, stream, x, rng);
    hipLaunchKernelGGL(k_select,   dim3(NB),   dim3(NC), 0, stream, rng, sel);
    hipLaunchKernelGGL(k_zero,     dim3(3840), dim3(256), 0, stream, (uint4*)r1T, 983040);
    hipLaunchKernelGGL(k_conv1_mfma, dim3(224), dim3(512), 0, stream,
                       xT2, wT2, b1b, b2a, r1T);
    hipLaunchKernelGGL(k_pack_xup, dim3(1792), dim3(256), 0, stream, x, sel, b1a, xupT);
    hipLaunchKernelGGL(k_conv2_mfma, dim3(NB * 7), dim3(512), 0, stream,
                       r1T, xupT, wc2T, wupT, scale, b2b, out);
}

// Round 12
// 119.753 us; speedup vs baseline: 1.1573x; 1.0540x over previous
//
#include <hip/hip_runtime.h>

#define NB 32      // batch
#define NC 256     // planes
#define NO 128     // inplanes (output channels)
#define HH 28
#define HW 784     // 28*28
#define OH 56

typedef unsigned short u16;
typedef __attribute__((ext_vector_type(8))) short bf16x8;
typedef __attribute__((ext_vector_type(4))) float f32x4;
typedef __attribute__((ext_vector_type(8))) unsigned short u16x8;

#define MFMA(A,B,C) __builtin_amdgcn_mfma_f32_16x16x32_bf16(A,B,C,0,0,0)

__device__ __forceinline__ u16 f2bf(float f) {
    unsigned u = __float_as_uint(f);
    unsigned r = (u + 0x7fffu + ((u >> 16) & 1u)) >> 16;
    return (u16)r;
}

// ---------------------------------------------------------------------------
// ring-only zero of r1T pad cells (cells conv1 never writes):
// rows {0,29} all cx; rows 1..28 cx in {0,29,30,31}. One uint4 per (cx,ci8).
// 32b * 32cb * 176 cells = 180224 -> 704 blocks.
// ---------------------------------------------------------------------------
__global__ void k_zero_ring(uint4* __restrict__ r1T4) {
    int g = blockIdx.x * 256 + threadIdx.x;
    int i = g % 176;
    int bc = g / 176;                  // b*32 + cb
    int b = bc >> 5, cb = bc & 31;
    int row, cx;
    if (i < 32)      { row = 0;  cx = i; }
    else if (i < 64) { row = 29; cx = i - 32; }
    else {
        int j = i - 64;
        row = 1 + (j >> 2);
        int k = j & 3;
        cx = (k == 0) ? 0 : 28 + k;    // 0,29,30,31
    }
    r1T4[((b * 30 + row) * 32 + cb) * 32 + cx] = make_uint4(0, 0, 0, 0);
}

// ---------------------------------------------------------------------------
// Fused weight packs:
//  blocks [0,288):   wT2[tap][cb][o][ci]  = w2[c][o][2-dy][2-dx]
//  blocks [288,432): wc2T[s][cb][o][ci]   = w1[c][o][tap_s], s->taps {0,2,6,8,1,7,3,5,4}
//  blocks [432,464): wupT[p][kb][o][ki]   = wup[k][o][p]
// ---------------------------------------------------------------------------
__global__ void k_pack_weights(const float* __restrict__ w2, const float* __restrict__ w1,
                               const float* __restrict__ wup,
                               u16* __restrict__ wT2, u16* __restrict__ wc2T,
                               u16* __restrict__ wupT) {
    int blk = blockIdx.x;
    if (blk < 288) {
        int g = blk * 256 + threadIdx.x;          // 9*32*256
        int o = g & 255;
        int cb = (g >> 8) & 31;
        int tap = g >> 13;
        int u = 2 - tap / 3, v = 2 - tap % 3;
        u16x8 out;
#pragma unroll
        for (int ci = 0; ci < 8; ++ci) {
            int c = cb * 8 + ci;
            out[ci] = f2bf(w2[((c * NC + o) * 3 + u) * 3 + v]);
        }
        *(u16x8*)(wT2 + (size_t)g * 8) = out;
    } else if (blk < 432) {
        const int taps[9] = {0, 2, 6, 8, 1, 7, 3, 5, 4};
        int g = (blk - 288) * 256 + threadIdx.x;  // 9*32*128
        int o = g & 127;
        int cb = (g >> 7) & 31;
        int s = g >> 12;
        int tap = taps[s];
        u16x8 out;
#pragma unroll
        for (int ci = 0; ci < 8; ++ci) {
            int c = cb * 8 + ci;
            out[ci] = f2bf(w1[(c * NO + o) * 9 + tap]);
        }
        *(u16x8*)(wc2T + (size_t)g * 8) = out;
    } else {
        int g = (blk - 432) * 256 + threadIdx.x;  // 4*16*128
        int o = g & 127;
        int kb = (g >> 7) & 15;
        int p = g >> 11;
        u16x8 out;
#pragma unroll
        for (int ki = 0; ki < 8; ++ki) {
            int k = kb * 8 + ki;
            out[ki] = f2bf(wup[(k * NO + o) * 4 + p]);
        }
        *(u16x8*)(wupT + (size_t)g * 8) = out;
    }
}

// ---------------------------------------------------------------------------
// Pack x: xT2[b][ry 0..29][cb][cx 0..31][ci], value = x[b][c][ry-1][cx-1]+b1a or 0
// ---------------------------------------------------------------------------
__global__ void k_pack_x(const float* __restrict__ x, const float* __restrict__ pb1a,
                         u16* __restrict__ xT2) {
    int g = blockIdx.x * 256 + threadIdx.x;          // 32*30*32*32 = 983040
    float b1a = pb1a[0];
    int cx = g & 31;
    int cb = (g >> 5) & 31;
    int bry = g >> 10;
    int b = bry / 30;
    int ry = bry - b * 30;
    int y = ry - 1, xx = cx - 1;
    bool valid = (y >= 0 && y < HH && xx >= 0 && xx < HH);
    const float* xb = x + (size_t)b * NC * HW + (valid ? y * 28 + xx : 0);
    u16x8 out;
#pragma unroll
    for (int ci = 0; ci < 8; ++ci) {
        float f = valid ? xb[(cb * 8 + ci) * HW] + b1a : 0.f;
        out[ci] = f2bf(f);
    }
    *(u16x8*)(xT2 + (size_t)g * 8) = out;
}

// ---------------------------------------------------------------------------
// Gather-pack selected channels: xupT[b][qy][kb][cx][ki] = x[b][sel[k]][qy][cx]+b1a
// ---------------------------------------------------------------------------
__global__ void k_pack_xup(const float* __restrict__ x, const int* __restrict__ sel,
                           const float* __restrict__ pb1a, u16* __restrict__ xupT) {
    int g = blockIdx.x * 256 + threadIdx.x;          // 32*28*16*32 = 458752
    float b1a = pb1a[0];
    int cx = g & 31;
    int kb = (g >> 5) & 15;
    int qyb = g >> 9;
    int b = qyb / 28;
    int qy = qyb - b * 28;
    bool valid = cx < 28;
    const int* selb = sel + b * NO;
    const float* xb = x + (size_t)b * NC * HW + qy * 28 + (valid ? cx : 0);
    u16x8 out;
#pragma unroll
    for (int ki = 0; ki < 8; ++ki) {
        int ch = selb[kb * 8 + ki];
        float f = valid ? xb[ch * HW] + b1a : 0.f;
        out[ki] = f2bf(f);
    }
    *(u16x8*)(xupT + (size_t)g * 8) = out;
}

// ---------------------------------------------------------------------------
// K1: per-(b,c) range
// ---------------------------------------------------------------------------
__global__ void k_range(const float* __restrict__ x, float* __restrict__ rng) {
    int bc = blockIdx.x;
    int t = threadIdx.x;
    const float* p = x + (size_t)bc * HW;
    float mx = -1e30f, mn = 1e30f;
    for (int i = t; i < HW; i += 256) {
        float v = p[i];
        mx = fmaxf(mx, v);
        mn = fminf(mn, v);
    }
    __shared__ float smx[256], smn[256];
    smx[t] = mx; smn[t] = mn;
    __syncthreads();
    for (int s = 128; s > 0; s >>= 1) {
        if (t < s) {
            smx[t] = fmaxf(smx[t], smx[t + s]);
            smn[t] = fminf(smn[t], smn[t + s]);
        }
        __syncthreads();
    }
    if (t == 0) rng[bc] = smx[0] - smn[0];
}

// ---------------------------------------------------------------------------
// K2: stable argsort rank; keep top half ascending
// ---------------------------------------------------------------------------
__global__ void k_select(const float* __restrict__ rng, int* __restrict__ sel) {
    int b = blockIdx.x;
    int c = threadIdx.x;
    __shared__ float s[NC];
    s[c] = rng[b * NC + c];
    __syncthreads();
    float v = s[c];
    int rank = 0;
    for (int j = 0; j < NC; ++j) {
        float u = s[j];
        rank += (u < v) || (u == v && j < c);
    }
    if (rank >= NC / 2) sel[b * (NC / 2) + (rank - NC / 2)] = c;
}

// ---------------------------------------------------------------------------
// conv1 via MFMA, occupancy + LDS combined:
//  - o split across 2 blocks (og): grid 448 = 32b x 7rg x 2og
//  - A-slab halved to 48KB (128 channels), restaged once (half loop)
//  - 2 blocks/CU co-resident -> 4 waves/SIMD for pipe overlap
//  8 waves = 2wpi x 4wo; wave = 4pt x 2ot, acc 32 VGPR.
// ---------------------------------------------------------------------------
__global__ __launch_bounds__(512, 4) void k_conv1_mfma(
    const u16* __restrict__ xT2, const u16* __restrict__ wT2,
    const float* __restrict__ pb1b, const float* __restrict__ pb2a,
    u16* __restrict__ r1T)
{
    __shared__ u16 sA[6 * 16 * 32 * 8];   // 49152 B: [row6][cb16][cx32][ci8]
    int tid = threadIdx.x;
    int wave = tid >> 6, lane = tid & 63;
    int wpi = wave >> 2;              // 0..1: rows {2wpi, 2wpi+1}
    int wo = wave & 3;                // 0..3: o-group of 32
    int l15 = lane & 15, lg = lane >> 4;

    int idx = blockIdx.x;             // 448
    int b = idx / 14;
    int rem = idx - b * 14;
    int rg = rem >> 1;
    int og = rem & 1;
    int y0 = rg * 4;

    float b1b = pb1b[0], b2a = pb2a[0];

    int bOff[2];
#pragma unroll
    for (int ot = 0; ot < 2; ++ot)
        bOff[ot] = (lg * 256 + (og * 128 + wo * 32 + ot * 16 + l15)) * 16;

    f32x4 acc[4][2] = {};   // [pt = m*2+h][ot]
    const char* wq = (const char*)wT2;
    const char* ap0 = (const char*)sA;
    const uint4* gx = (const uint4*)xT2;
    uint4* dst = (uint4*)sA;

    for (int half = 0; half < 2; ++half) {
        if (half) __syncthreads();    // previous compute done before overwrite
#pragma unroll
        for (int i = 0; i < 6; ++i)
            dst[tid + i * 512] = gx[(b * 30 + y0 + i) * 1024 + half * 512 + tid];
        __syncthreads();

        for (int cc = 0; cc < 128; cc += 32) {
            int c0 = half * 128 + cc;
#pragma unroll
            for (int dy = 0; dy < 3; ++dy) {
#pragma unroll
                for (int dx = 0; dx < 3; ++dx) {
                    int tap = dy * 3 + dx;
                    bf16x8 w[2];
#pragma unroll
                    for (int ot = 0; ot < 2; ++ot)
                        w[ot] = *(const bf16x8*)(wq + (bOff[ot] + tap * 131072 + c0 * 512));
                    bf16x8 a[2][2];
#pragma unroll
                    for (int m = 0; m < 2; ++m)
#pragma unroll
                        for (int h = 0; h < 2; ++h)
                            a[m][h] = *(const bf16x8*)(ap0 +
                                (2 * wpi + m + dy) * 8192 + cc * 64 + lg * 512 +
                                (h * 16 + l15 + dx) * 16);
#pragma unroll
                    for (int m = 0; m < 2; ++m)
#pragma unroll
                        for (int h = 0; h < 2; ++h)
#pragma unroll
                            for (int ot = 0; ot < 2; ++ot)
                                acc[m * 2 + h][ot] = MFMA(a[m][h], w[ot], acc[m * 2 + h][ot]);
                }
            }
        }
    }

    // epilogue: relu(acc+b1b)+b2a -> r1T[b][y+1][o/8][x+1][o%8]
#pragma unroll
    for (int m = 0; m < 2; ++m)
#pragma unroll
        for (int h = 0; h < 2; ++h) {
            int y = y0 + 2 * wpi + m;
            int x0 = h * 16 + lg * 4;
            if (x0 >= 28) continue;
#pragma unroll
            for (int ot = 0; ot < 2; ++ot) {
                int o = og * 128 + wo * 32 + ot * 16 + l15;
                size_t base = ((((size_t)b * 30 + y + 1) * 32 + (o >> 3)) * 32 + (x0 + 1)) * 8 + (o & 7);
#pragma unroll
                for (int r = 0; r < 4; ++r) {
                    float f = fmaxf(acc[m * 2 + h][ot][r] + b1b, 0.f) + b2a;
                    r1T[base + (size_t)r * 8] = f2bf(f);
                }
            }
        }
}

// ---------------------------------------------------------------------------
// conv2 + upsample via MFMA, A-slab (r1T rows y0..y0+4) staged in LDS (80KB).
// (unchanged control from r11)
// ---------------------------------------------------------------------------
__global__ __launch_bounds__(512, 2) void k_conv2_mfma(
    const u16* __restrict__ r1T, const u16* __restrict__ xupT,
    const u16* __restrict__ wc2T, const u16* __restrict__ wupT,
    const float* __restrict__ pscale, const float* __restrict__ pb2b,
    float* __restrict__ out)
{
    __shared__ uint4 sA2[5120];       // 81920 B: padded rows y0..y0+4
    int tid = threadIdx.x;
    int wave = tid >> 6, lane = tid & 63;
    int wpi = wave >> 2;
    int wo = wave & 3;
    int l15 = lane & 15, lg = lane >> 4;

    int b = blockIdx.x / 7;
    int rg = blockIdx.x - b * 7;
    int y0 = rg * 4;

    float scale = pscale[0], b2b = pb2b[0];

    // stage 5-row r1T slab (contiguous 80KB)
    {
        const uint4* src = (const uint4*)(r1T + (size_t)(b * 30 + y0) * 8192);
#pragma unroll
        for (int i = 0; i < 10; ++i)
            sA2[tid + i * 512] = src[tid + i * 512];
    }
    __syncthreads();

    f32x4 acc[4][4][2] = {};   // [parity][pixel-tile][o-tile]

    const char* sp = (const char*)sA2;
    const char* wp = (const char*)wc2T;

    int aBase[4];
#pragma unroll
    for (int pt = 0; pt < 4; ++pt) {
        int rel = 2 * wpi + (pt >> 1) + 1;    // (qy+1) - y0
        int qt = pt & 1;
        aBase[pt] = ((rel * 32 + lg) * 32 + (qt * 16 + l15 + 1)) * 16;
    }
    int bBase = (lg * 128 + wo * 32 + l15) * 16;

    for (int c0 = 0; c0 < 256; c0 += 32) {
        bf16x8 w[9][2];
#pragma unroll
        for (int s = 0; s < 9; ++s)
#pragma unroll
            for (int ot = 0; ot < 2; ++ot)
                w[s][ot] = *(const bf16x8*)(wp + (bBase + s * 65536 + c0 * 256 + ot * 256));
#pragma unroll
        for (int pt = 0; pt < 4; ++pt) {
            const char* ap = sp + (aBase[pt] + c0 * 64);
            bf16x8 aD = *(const bf16x8*)(ap);
            bf16x8 aC = *(const bf16x8*)(ap - 16);
            bf16x8 aB = *(const bf16x8*)(ap - 16384);
            bf16x8 aA = *(const bf16x8*)(ap - 16400);
#pragma unroll
            for (int ot = 0; ot < 2; ++ot) {
                acc[0][pt][ot] = MFMA(aD, w[0][ot], acc[0][pt][ot]);
                acc[0][pt][ot] = MFMA(aC, w[1][ot], acc[0][pt][ot]);
                acc[0][pt][ot] = MFMA(aB, w[2][ot], acc[0][pt][ot]);
                acc[0][pt][ot] = MFMA(aA, w[3][ot], acc[0][pt][ot]);
                acc[1][pt][ot] = MFMA(aD, w[4][ot], acc[1][pt][ot]);
                acc[1][pt][ot] = MFMA(aB, w[5][ot], acc[1][pt][ot]);
                acc[2][pt][ot] = MFMA(aD, w[6][ot], acc[2][pt][ot]);
                acc[2][pt][ot] = MFMA(aC, w[7][ot], acc[2][pt][ot]);
                acc[3][pt][ot] = MFMA(aD, w[8][ot], acc[3][pt][ot]);
            }
        }
    }

    // mid-transform: pad-zero / scale+b2b (before upsample accumulation)
#pragma unroll
    for (int pt = 0; pt < 4; ++pt) {
        int qy = y0 + 2 * wpi + (pt >> 1);
        int qt = pt & 1;
        int qx0 = qt * 16 + lg * 4;
        bool zr = (qy == 0);
#pragma unroll
        for (int ot = 0; ot < 2; ++ot)
#pragma unroll
            for (int r = 0; r < 4; ++r) {
                bool zc = (qx0 + r == 0);
                float a0 = acc[0][pt][ot][r], a1 = acc[1][pt][ot][r];
                float a2 = acc[2][pt][ot][r], a3 = acc[3][pt][ot][r];
                acc[0][pt][ot][r] = (zr || zc) ? 0.f : fmaf(a0, scale, b2b);
                acc[1][pt][ot][r] = zr ? 0.f : fmaf(a1, scale, b2b);
                acc[2][pt][ot][r] = zc ? 0.f : fmaf(a2, scale, b2b);
                acc[3][pt][ot][r] = fmaf(a3, scale, b2b);
            }
    }

    // upsample accumulation (xupT/wupT from global; L2-resident)
    const char* up = (const char*)xupT;
    const char* wu = (const char*)wupT;
    int uBaseA[4];
#pragma unroll
    for (int pt = 0; pt < 4; ++pt) {
        int qy = y0 + 2 * wpi + (pt >> 1);
        int qt = pt & 1;
        uBaseA[pt] = (((b * 28 + qy) * 16 + lg) * 32 + (qt * 16 + l15)) * 16;
    }
    for (int k0 = 0; k0 < 128; k0 += 32) {
        bf16x8 wb[4][2];
#pragma unroll
        for (int p = 0; p < 4; ++p)
#pragma unroll
            for (int ot = 0; ot < 2; ++ot)
                wb[p][ot] = *(const bf16x8*)(wu + (bBase + p * 32768 + k0 * 256 + ot * 256));
#pragma unroll
        for (int pt = 0; pt < 4; ++pt) {
            bf16x8 aU = *(const bf16x8*)(up + (uBaseA[pt] + k0 * 64));
#pragma unroll
            for (int p = 0; p < 4; ++p)
#pragma unroll
                for (int ot = 0; ot < 2; ++ot)
                    acc[p][pt][ot] = MFMA(aU, wb[p][ot], acc[p][pt][ot]);
        }
    }

    // relu + store
#pragma unroll
    for (int pt = 0; pt < 4; ++pt) {
        int qy = y0 + 2 * wpi + (pt >> 1);
        int qt = pt & 1;
        int qx0 = qt * 16 + lg * 4;
        if (qx0 >= 28) continue;
#pragma unroll
        for (int ot = 0; ot < 2; ++ot) {
            int o = wo * 32 + ot * 16 + l15;
            size_t base = ((size_t)(b * NO + o) * OH + 2 * qy) * OH + 2 * qx0;
#pragma unroll
            for (int r = 0; r < 4; ++r) {
                float2 v0 = { fmaxf(acc[0][pt][ot][r], 0.f), fmaxf(acc[1][pt][ot][r], 0.f) };
                float2 v1 = { fmaxf(acc[2][pt][ot][r], 0.f), fmaxf(acc[3][pt][ot][r], 0.f) };
                *reinterpret_cast<float2*>(&out[base + 2 * r]) = v0;
                *reinterpret_cast<float2*>(&out[base + OH + 2 * r]) = v1;
            }
        }
    }
}

// ---------------------------------------------------------------------------
extern "C" void kernel_launch(void* const* d_in, const int* in_sizes, int n_in,
                              void* d_out, int out_size, void* d_ws, size_t ws_size,
                              hipStream_t stream)
{
    const float* x     = (const float*)d_in[0];
    const float* w2    = (const float*)d_in[1];
    const float* w1    = (const float*)d_in[2];
    const float* wup   = (const float*)d_in[3];
    const float* b1a   = (const float*)d_in[4];
    const float* b1b   = (const float*)d_in[5];
    const float* b2a   = (const float*)d_in[6];
    const float* b2b   = (const float*)d_in[7];
    const float* scale = (const float*)d_in[8];

    char* ws = (char*)d_ws;
    u16* xT2   = (u16*)(ws);                 // 15,728,640 B
    u16* r1T   = (u16*)(ws + 15728640);      // 15,728,640 B
    u16* xupT  = (u16*)(ws + 31457280);      //  7,340,032 B
    u16* wT2   = (u16*)(ws + 38797312);      //  1,179,648 B
    u16* wc2T  = (u16*)(ws + 39976960);      //    589,824 B
    u16* wupT  = (u16*)(ws + 40566784);      //    131,072 B
    float* rng = (float*)(ws + 40697856);    //     32,768 B
    int* sel   = (int*)(ws + 40730624);      //     16,384 B
    float* out = (float*)d_out;

    hipLaunchKernelGGL(k_pack_weights, dim3(464), dim3(256), 0, stream,
                       w2, w1, wup, wT2, wc2T, wupT);
    hipLaunchKernelGGL(k_pack_x,   dim3(3840), dim3(256), 0, stream, x, b1a, xT2);
    hipLaunchKernelGGL(k_range,    dim3(NB * NC), dim3(256), 0, stream, x, rng);
    hipLaunchKernelGGL(k_select,   dim3(NB),   dim3(NC), 0, stream, rng, sel);
    hipLaunchKernelGGL(k_zero_ring, dim3(704), dim3(256), 0, stream, (uint4*)r1T);
    hipLaunchKernelGGL(k_conv1_mfma, dim3(448), dim3(512), 0, stream,
                       xT2, wT2, b1b, b2a, r1T);
    hipLaunchKernelGGL(k_pack_xup, dim3(1792), dim3(256), 0, stream, x, sel, b1a, xupT);
    hipLaunchKernelGGL(k_conv2_mfma, dim3(NB * 7), dim3(512), 0, stream,
                       r1T, xupT, wc2T, wupT, scale, b2b, out);
}

// Round 13
// 114.335 us; speedup vs baseline: 1.2121x; 1.0474x over previous
//
#include <hip/hip_runtime.h>

#define NB 32      // batch
#define NC 256     // planes
#define NO 128     // inplanes (output channels)
#define HH 28
#define HW 784     // 28*28
#define OH 56

typedef unsigned short u16;
typedef __attribute__((ext_vector_type(8))) short bf16x8;
typedef __attribute__((ext_vector_type(4))) float f32x4;
typedef __attribute__((ext_vector_type(8))) unsigned short u16x8;

#define MFMA(A,B,C) __builtin_amdgcn_mfma_f32_16x16x32_bf16(A,B,C,0,0,0)

__device__ __forceinline__ u16 f2bf(float f) {
    unsigned u = __float_as_uint(f);
    unsigned r = (u + 0x7fffu + ((u >> 16) & 1u)) >> 16;
    return (u16)r;
}

// ---------------------------------------------------------------------------
// k_misc: fused weight packs + r1T ring zero (grid-concat, 1168 blocks):
//  [0,288):    wT2[tap][cb][o][ci]  = w2[c][o][2-dy][2-dx]
//  [288,432):  wc2T[s][cb][o][ci]   = w1[c][o][tap_s], s->taps {0,2,6,8,1,7,3,5,4}
//  [432,464):  wupT[p][kb][o][ki]   = wup[k][o][p]
//  [464,1168): zero r1T pad ring (rows {0,29} all cx; rows 1..28 cx {0,29,30,31})
// ---------------------------------------------------------------------------
__global__ void k_misc(const float* __restrict__ w2, const float* __restrict__ w1,
                       const float* __restrict__ wup,
                       u16* __restrict__ wT2, u16* __restrict__ wc2T,
                       u16* __restrict__ wupT, uint4* __restrict__ r1T4) {
    int blk = blockIdx.x;
    if (blk < 288) {
        int g = blk * 256 + threadIdx.x;          // 9*32*256
        int o = g & 255;
        int cb = (g >> 8) & 31;
        int tap = g >> 13;
        int u = 2 - tap / 3, v = 2 - tap % 3;
        u16x8 out;
#pragma unroll
        for (int ci = 0; ci < 8; ++ci) {
            int c = cb * 8 + ci;
            out[ci] = f2bf(w2[((c * NC + o) * 3 + u) * 3 + v]);
        }
        *(u16x8*)(wT2 + (size_t)g * 8) = out;
    } else if (blk < 432) {
        const int taps[9] = {0, 2, 6, 8, 1, 7, 3, 5, 4};
        int g = (blk - 288) * 256 + threadIdx.x;  // 9*32*128
        int o = g & 127;
        int cb = (g >> 7) & 31;
        int s = g >> 12;
        int tap = taps[s];
        u16x8 out;
#pragma unroll
        for (int ci = 0; ci < 8; ++ci) {
            int c = cb * 8 + ci;
            out[ci] = f2bf(w1[(c * NO + o) * 9 + tap]);
        }
        *(u16x8*)(wc2T + (size_t)g * 8) = out;
    } else if (blk < 464) {
        int g = (blk - 432) * 256 + threadIdx.x;  // 4*16*128
        int o = g & 127;
        int kb = (g >> 7) & 15;
        int p = g >> 11;
        u16x8 out;
#pragma unroll
        for (int ki = 0; ki < 8; ++ki) {
            int k = kb * 8 + ki;
            out[ki] = f2bf(wup[(k * NO + o) * 4 + p]);
        }
        *(u16x8*)(wupT + (size_t)g * 8) = out;
    } else {
        int g = (blk - 464) * 256 + threadIdx.x;  // 180224
        int i = g % 176;
        int bc = g / 176;                  // b*32 + cb
        int b = bc >> 5, cb = bc & 31;
        int row, cx;
        if (i < 32)      { row = 0;  cx = i; }
        else if (i < 64) { row = 29; cx = i - 32; }
        else {
            int j = i - 64;
            row = 1 + (j >> 2);
            int k = j & 3;
            cx = (k == 0) ? 0 : 28 + k;    // 0,29,30,31
        }
        r1T4[((b * 30 + row) * 32 + cb) * 32 + cx] = make_uint4(0, 0, 0, 0);
    }
}

// ---------------------------------------------------------------------------
// k_prep_x: fused x-pack + per-channel range. Block = (b, cb), 1024 blocks.
// Stage 8 channels (25 KB) in LDS once; reduce max/min per channel -> rng;
// emit padded xT2[b][ry][cb][cx][ci] from LDS. One 25.7MB read of x total.
// ---------------------------------------------------------------------------
__global__ __launch_bounds__(256) void k_prep_x(
    const float* __restrict__ x, const float* __restrict__ pb1a,
    u16* __restrict__ xT2, float* __restrict__ rng)
{
    __shared__ float sx[8][HW];        // 25088 B
    __shared__ float smx[8][4], smn[8][4];
    int t = threadIdx.x;
    int b = blockIdx.x >> 5, cb = blockIdx.x & 31;
    float b1a = pb1a[0];
    const float* xb = x + ((size_t)b * NC + cb * 8) * HW;

    float mx[8], mn[8];
#pragma unroll
    for (int ci = 0; ci < 8; ++ci) { mx[ci] = -1e30f; mn[ci] = 1e30f; }
#pragma unroll
    for (int ci = 0; ci < 8; ++ci) {
        for (int px = t; px < HW; px += 256) {
            float v = xb[ci * HW + px];
            sx[ci][px] = v;
            mx[ci] = fmaxf(mx[ci], v);
            mn[ci] = fminf(mn[ci], v);
        }
    }
    int lane = t & 63, wv = t >> 6;
#pragma unroll
    for (int ci = 0; ci < 8; ++ci) {
        float a = mx[ci], i = mn[ci];
        for (int off = 32; off; off >>= 1) {
            a = fmaxf(a, __shfl_down(a, off, 64));
            i = fminf(i, __shfl_down(i, off, 64));
        }
        if (lane == 0) { smx[ci][wv] = a; smn[ci][wv] = i; }
    }
    __syncthreads();
    if (t < 8) {
        float a = fmaxf(fmaxf(smx[t][0], smx[t][1]), fmaxf(smx[t][2], smx[t][3]));
        float i = fminf(fminf(smn[t][0], smn[t][1]), fminf(smn[t][2], smn[t][3]));
        rng[b * NC + cb * 8 + t] = a - i;
    }
    // write xT2 from LDS: 960 groups (ry,cx)
    for (int g = t; g < 960; g += 256) {
        int ry = g >> 5, cx = g & 31;
        int y = ry - 1, xx = cx - 1;
        bool valid = (y >= 0 && y < HH && xx >= 0 && xx < HH);
        u16x8 out;
#pragma unroll
        for (int ci = 0; ci < 8; ++ci) {
            float f = valid ? sx[ci][y * 28 + xx] + b1a : 0.f;
            out[ci] = f2bf(f);
        }
        *(u16x8*)(xT2 + ((((size_t)b * 30 + ry) * 32 + cb) * 32 + cx) * 8) = out;
    }
}

// ---------------------------------------------------------------------------
// Gather-pack selected channels: xupT[b][qy][kb][cx][ki] = x[b][sel[k]][qy][cx]+b1a
// ---------------------------------------------------------------------------
__global__ void k_pack_xup(const float* __restrict__ x, const int* __restrict__ sel,
                           const float* __restrict__ pb1a, u16* __restrict__ xupT) {
    int g = blockIdx.x * 256 + threadIdx.x;          // 32*28*16*32 = 458752
    float b1a = pb1a[0];
    int cx = g & 31;
    int kb = (g >> 5) & 15;
    int qyb = g >> 9;
    int b = qyb / 28;
    int qy = qyb - b * 28;
    bool valid = cx < 28;
    const int* selb = sel + b * NO;
    const float* xb = x + (size_t)b * NC * HW + qy * 28 + (valid ? cx : 0);
    u16x8 out;
#pragma unroll
    for (int ki = 0; ki < 8; ++ki) {
        int ch = selb[kb * 8 + ki];
        float f = valid ? xb[ch * HW] + b1a : 0.f;
        out[ki] = f2bf(f);
    }
    *(u16x8*)(xupT + (size_t)g * 8) = out;
}

// ---------------------------------------------------------------------------
// K2: stable argsort rank; keep top half ascending
// ---------------------------------------------------------------------------
__global__ void k_select(const float* __restrict__ rng, int* __restrict__ sel) {
    int b = blockIdx.x;
    int c = threadIdx.x;
    __shared__ float s[NC];
    s[c] = rng[b * NC + c];
    __syncthreads();
    float v = s[c];
    int rank = 0;
    for (int j = 0; j < NC; ++j) {
        float u = s[j];
        rank += (u < v) || (u == v && j < c);
    }
    if (rank >= NC / 2) sel[b * (NC / 2) + (rank - NC / 2)] = c;
}

// ---------------------------------------------------------------------------
// conv1 via MFMA (r12 structure, frozen control):
//  o split (og), grid 448; A-slab 48KB (128ch half, restaged once); 4 waves/SIMD.
// ---------------------------------------------------------------------------
__global__ __launch_bounds__(512, 4) void k_conv1_mfma(
    const u16* __restrict__ xT2, const u16* __restrict__ wT2,
    const float* __restrict__ pb1b, const float* __restrict__ pb2a,
    u16* __restrict__ r1T)
{
    __shared__ u16 sA[6 * 16 * 32 * 8];   // 49152 B
    int tid = threadIdx.x;
    int wave = tid >> 6, lane = tid & 63;
    int wpi = wave >> 2;
    int wo = wave & 3;
    int l15 = lane & 15, lg = lane >> 4;

    int idx = blockIdx.x;             // 448
    int b = idx / 14;
    int rem = idx - b * 14;
    int rg = rem >> 1;
    int og = rem & 1;
    int y0 = rg * 4;

    float b1b = pb1b[0], b2a = pb2a[0];

    int bOff[2];
#pragma unroll
    for (int ot = 0; ot < 2; ++ot)
        bOff[ot] = (lg * 256 + (og * 128 + wo * 32 + ot * 16 + l15)) * 16;

    f32x4 acc[4][2] = {};
    const char* wq = (const char*)wT2;
    const char* ap0 = (const char*)sA;
    const uint4* gx = (const uint4*)xT2;
    uint4* dst = (uint4*)sA;

    for (int half = 0; half < 2; ++half) {
        if (half) __syncthreads();
#pragma unroll
        for (int i = 0; i < 6; ++i)
            dst[tid + i * 512] = gx[(b * 30 + y0 + i) * 1024 + half * 512 + tid];
        __syncthreads();

        for (int cc = 0; cc < 128; cc += 32) {
            int c0 = half * 128 + cc;
#pragma unroll
            for (int dy = 0; dy < 3; ++dy) {
#pragma unroll
                for (int dx = 0; dx < 3; ++dx) {
                    int tap = dy * 3 + dx;
                    bf16x8 w[2];
#pragma unroll
                    for (int ot = 0; ot < 2; ++ot)
                        w[ot] = *(const bf16x8*)(wq + (bOff[ot] + tap * 131072 + c0 * 512));
                    bf16x8 a[2][2];
#pragma unroll
                    for (int m = 0; m < 2; ++m)
#pragma unroll
                        for (int h = 0; h < 2; ++h)
                            a[m][h] = *(const bf16x8*)(ap0 +
                                (2 * wpi + m + dy) * 8192 + cc * 64 + lg * 512 +
                                (h * 16 + l15 + dx) * 16);
#pragma unroll
                    for (int m = 0; m < 2; ++m)
#pragma unroll
                        for (int h = 0; h < 2; ++h)
#pragma unroll
                            for (int ot = 0; ot < 2; ++ot)
                                acc[m * 2 + h][ot] = MFMA(a[m][h], w[ot], acc[m * 2 + h][ot]);
                }
            }
        }
    }

#pragma unroll
    for (int m = 0; m < 2; ++m)
#pragma unroll
        for (int h = 0; h < 2; ++h) {
            int y = y0 + 2 * wpi + m;
            int x0 = h * 16 + lg * 4;
            if (x0 >= 28) continue;
#pragma unroll
            for (int ot = 0; ot < 2; ++ot) {
                int o = og * 128 + wo * 32 + ot * 16 + l15;
                size_t base = ((((size_t)b * 30 + y + 1) * 32 + (o >> 3)) * 32 + (x0 + 1)) * 8 + (o & 7);
#pragma unroll
                for (int r = 0; r < 4; ++r) {
                    float f = fmaxf(acc[m * 2 + h][ot][r] + b1b, 0.f) + b2a;
                    r1T[base + (size_t)r * 8] = f2bf(f);
                }
            }
        }
}

// ---------------------------------------------------------------------------
// conv2 + upsample via MFMA, A-slab in LDS (r11 structure, frozen control).
// ---------------------------------------------------------------------------
__global__ __launch_bounds__(512, 2) void k_conv2_mfma(
    const u16* __restrict__ r1T, const u16* __restrict__ xupT,
    const u16* __restrict__ wc2T, const u16* __restrict__ wupT,
    const float* __restrict__ pscale, const float* __restrict__ pb2b,
    float* __restrict__ out)
{
    __shared__ uint4 sA2[5120];       // 81920 B
    int tid = threadIdx.x;
    int wave = tid >> 6, lane = tid & 63;
    int wpi = wave >> 2;
    int wo = wave & 3;
    int l15 = lane & 15, lg = lane >> 4;

    int b = blockIdx.x / 7;
    int rg = blockIdx.x - b * 7;
    int y0 = rg * 4;

    float scale = pscale[0], b2b = pb2b[0];

    {
        const uint4* src = (const uint4*)(r1T + (size_t)(b * 30 + y0) * 8192);
#pragma unroll
        for (int i = 0; i < 10; ++i)
            sA2[tid + i * 512] = src[tid + i * 512];
    }
    __syncthreads();

    f32x4 acc[4][4][2] = {};

    const char* sp = (const char*)sA2;
    const char* wp = (const char*)wc2T;

    int aBase[4];
#pragma unroll
    for (int pt = 0; pt < 4; ++pt) {
        int rel = 2 * wpi + (pt >> 1) + 1;
        int qt = pt & 1;
        aBase[pt] = ((rel * 32 + lg) * 32 + (qt * 16 + l15 + 1)) * 16;
    }
    int bBase = (lg * 128 + wo * 32 + l15) * 16;

    for (int c0 = 0; c0 < 256; c0 += 32) {
        bf16x8 w[9][2];
#pragma unroll
        for (int s = 0; s < 9; ++s)
#pragma unroll
            for (int ot = 0; ot < 2; ++ot)
                w[s][ot] = *(const bf16x8*)(wp + (bBase + s * 65536 + c0 * 256 + ot * 256));
#pragma unroll
        for (int pt = 0; pt < 4; ++pt) {
            const char* ap = sp + (aBase[pt] + c0 * 64);
            bf16x8 aD = *(const bf16x8*)(ap);
            bf16x8 aC = *(const bf16x8*)(ap - 16);
            bf16x8 aB = *(const bf16x8*)(ap - 16384);
            bf16x8 aA = *(const bf16x8*)(ap - 16400);
#pragma unroll
            for (int ot = 0; ot < 2; ++ot) {
                acc[0][pt][ot] = MFMA(aD, w[0][ot], acc[0][pt][ot]);
                acc[0][pt][ot] = MFMA(aC, w[1][ot], acc[0][pt][ot]);
                acc[0][pt][ot] = MFMA(aB, w[2][ot], acc[0][pt][ot]);
                acc[0][pt][ot] = MFMA(aA, w[3][ot], acc[0][pt][ot]);
                acc[1][pt][ot] = MFMA(aD, w[4][ot], acc[1][pt][ot]);
                acc[1][pt][ot] = MFMA(aB, w[5][ot], acc[1][pt][ot]);
                acc[2][pt][ot] = MFMA(aD, w[6][ot], acc[2][pt][ot]);
                acc[2][pt][ot] = MFMA(aC, w[7][ot], acc[2][pt][ot]);
                acc[3][pt][ot] = MFMA(aD, w[8][ot], acc[3][pt][ot]);
            }
        }
    }

#pragma unroll
    for (int pt = 0; pt < 4; ++pt) {
        int qy = y0 + 2 * wpi + (pt >> 1);
        int qt = pt & 1;
        int qx0 = qt * 16 + lg * 4;
        bool zr = (qy == 0);
#pragma unroll
        for (int ot = 0; ot < 2; ++ot)
#pragma unroll
            for (int r = 0; r < 4; ++r) {
                bool zc = (qx0 + r == 0);
                float a0 = acc[0][pt][ot][r], a1 = acc[1][pt][ot][r];
                float a2 = acc[2][pt][ot][r], a3 = acc[3][pt][ot][r];
                acc[0][pt][ot][r] = (zr || zc) ? 0.f : fmaf(a0, scale, b2b);
                acc[1][pt][ot][r] = zr ? 0.f : fmaf(a1, scale, b2b);
                acc[2][pt][ot][r] = zc ? 0.f : fmaf(a2, scale, b2b);
                acc[3][pt][ot][r] = fmaf(a3, scale, b2b);
            }
    }

    const char* up = (const char*)xupT;
    const char* wu = (const char*)wupT;
    int uBaseA[4];
#pragma unroll
    for (int pt = 0; pt < 4; ++pt) {
        int qy = y0 + 2 * wpi + (pt >> 1);
        int qt = pt & 1;
        uBaseA[pt] = (((b * 28 + qy) * 16 + lg) * 32 + (qt * 16 + l15)) * 16;
    }
    for (int k0 = 0; k0 < 128; k0 += 32) {
        bf16x8 wb[4][2];
#pragma unroll
        for (int p = 0; p < 4; ++p)
#pragma unroll
            for (int ot = 0; ot < 2; ++ot)
                wb[p][ot] = *(const bf16x8*)(wu + (bBase + p * 32768 + k0 * 256 + ot * 256));
#pragma unroll
        for (int pt = 0; pt < 4; ++pt) {
            bf16x8 aU = *(const bf16x8*)(up + (uBaseA[pt] + k0 * 64));
#pragma unroll
            for (int p = 0; p < 4; ++p)
#pragma unroll
                for (int ot = 0; ot < 2; ++ot)
                    acc[p][pt][ot] = MFMA(aU, wb[p][ot], acc[p][pt][ot]);
        }
    }

#pragma unroll
    for (int pt = 0; pt < 4; ++pt) {
        int qy = y0 + 2 * wpi + (pt >> 1);
        int qt = pt & 1;
        int qx0 = qt * 16 + lg * 4;
        if (qx0 >= 28) continue;
#pragma unroll
        for (int ot = 0; ot < 2; ++ot) {
            int o = wo * 32 + ot * 16 + l15;
            size_t base = ((size_t)(b * NO + o) * OH + 2 * qy) * OH + 2 * qx0;
#pragma unroll
            for (int r = 0; r < 4; ++r) {
                float2 v0 = { fmaxf(acc[0][pt][ot][r], 0.f), fmaxf(acc[1][pt][ot][r], 0.f) };
                float2 v1 = { fmaxf(acc[2][pt][ot][r], 0.f), fmaxf(acc[3][pt][ot][r], 0.f) };
                *reinterpret_cast<float2*>(&out[base + 2 * r]) = v0;
                *reinterpret_cast<float2*>(&out[base + OH + 2 * r]) = v1;
            }
        }
    }
}

// ---------------------------------------------------------------------------
extern "C" void kernel_launch(void* const* d_in, const int* in_sizes, int n_in,
                              void* d_out, int out_size, void* d_ws, size_t ws_size,
                              hipStream_t stream)
{
    const float* x     = (const float*)d_in[0];
    const float* w2    = (const float*)d_in[1];
    const float* w1    = (const float*)d_in[2];
    const float* wup   = (const float*)d_in[3];
    const float* b1a   = (const float*)d_in[4];
    const float* b1b   = (const float*)d_in[5];
    const float* b2a   = (const float*)d_in[6];
    const float* b2b   = (const float*)d_in[7];
    const float* scale = (const float*)d_in[8];

    char* ws = (char*)d_ws;
    u16* xT2   = (u16*)(ws);                 // 15,728,640 B
    u16* r1T   = (u16*)(ws + 15728640);      // 15,728,640 B
    u16* xupT  = (u16*)(ws + 31457280);      //  7,340,032 B
    u16* wT2   = (u16*)(ws + 38797312);      //  1,179,648 B
    u16* wc2T  = (u16*)(ws + 39976960);      //    589,824 B
    u16* wupT  = (u16*)(ws + 40566784);      //    131,072 B
    float* rng = (float*)(ws + 40697856);    //     32,768 B
    int* sel   = (int*)(ws + 40730624);      //     16,384 B
    float* out = (float*)d_out;

    hipLaunchKernelGGL(k_misc, dim3(1168), dim3(256), 0, stream,
                       w2, w1, wup, wT2, wc2T, wupT, (uint4*)r1T);
    hipLaunchKernelGGL(k_prep_x, dim3(1024), dim3(256), 0, stream, x, b1a, xT2, rng);
    hipLaunchKernelGGL(k_select, dim3(NB), dim3(NC), 0, stream, rng, sel);
    hipLaunchKernelGGL(k_pack_xup, dim3(1792), dim3(256), 0, stream, x, sel, b1a, xupT);
    hipLaunchKernelGGL(k_conv1_mfma, dim3(448), dim3(512), 0, stream,
                       xT2, wT2, b1b, b2a, r1T);
    hipLaunchKernelGGL(k_conv2_mfma, dim3(NB * 7), dim3(512), 0, stream,
                       r1T, xupT, wc2T, wupT, scale, b2b, out);
}